// Round 12
// baseline (507.600 us; speedup 1.0000x reference)
//
#include <hip/hip_runtime.h>
#include <stdint.h>

#define S_LEN 512
#define NT 9

typedef __attribute__((ext_vector_type(8)))  short          bf16x8;
typedef __attribute__((ext_vector_type(4)))  float          f32x4;
typedef __attribute__((ext_vector_type(4)))  unsigned short u16x4;

static __device__ __forceinline__ unsigned short f2bf(float f) {
    union { float f; unsigned u; } c; c.f = f;
    return (unsigned short)((c.u + 0x7fffu + ((c.u >> 16) & 1u)) >> 16); // RNE
}
static __device__ __forceinline__ float bf2f(unsigned short h) {
    union { unsigned u; float f; } c; c.u = ((unsigned)h) << 16;
    return c.f;
}
static __device__ __forceinline__ bf16x8 cvt8(const float* p) {
    f32x4 a = *(const f32x4*)p, b = *(const f32x4*)(p + 4);
    bf16x8 fr;
    fr[0]=(short)f2bf(a[0]); fr[1]=(short)f2bf(a[1]); fr[2]=(short)f2bf(a[2]); fr[3]=(short)f2bf(a[3]);
    fr[4]=(short)f2bf(b[0]); fr[5]=(short)f2bf(b[1]); fr[6]=(short)f2bf(b[2]); fr[7]=(short)f2bf(b[3]);
    return fr;
}
static __device__ __forceinline__ float sigf(float x) {
    return __builtin_amdgcn_rcpf(1.0f + __expf(-x));
}
static __device__ __forceinline__ float tanhf_(float x) {
    return 1.0f - 2.0f * __builtin_amdgcn_rcpf(1.0f + __expf(2.0f * x));
}

// Raw workgroup barrier that waits ONLY LDS ops (lgkmcnt) — global loads and
// stores stay in flight across it.
static __device__ __forceinline__ void wg_barrier_lds() {
    asm volatile("s_waitcnt lgkmcnt(0)" ::: "memory");
    __builtin_amdgcn_s_barrier();
    asm volatile("" ::: "memory");
}

// ---------------------------------------------------------------------------
// Kernel 0: ebf16[v][e] = bf16(embed[v][e]) — one streaming pass. Same f2bf
// as the old k_eg's A-conversion, so A-fragments stay bit-identical.
// ---------------------------------------------------------------------------
__global__ __launch_bounds__(256) void k_ebf(
    const float* __restrict__ embed, unsigned short* __restrict__ ebf)
{
    const size_t n4 = 1600000;   // 50000*128/4
    for (size_t i = blockIdx.x * 256 + threadIdx.x; i < n4; i += (size_t)2048 * 256) {
        f32x4 v = *(const f32x4*)(embed + i * 4);
        u16x4 o;
        o[0] = f2bf(v[0]); o[1] = f2bf(v[1]); o[2] = f2bf(v[2]); o[3] = f2bf(v[3]);
        *(u16x4*)(ebf + i * 4) = o;
    }
}

// ---------------------------------------------------------------------------
// Kernel 1: FUSED input-gate + recurrence. 64 WGs x 4 batch rows. The xg GEMM
// is folded into the step: per step, gather the 4 tokens' bf16 embed rows
// (from the L2/L3-resident ebf table, prefetched one full step ahead) and run
// an 8-deep MFMA chain acc = bias + emb@W_ih^T + h@W_hh^T (f32 accumulate;
// replaces the old bf16-rounded xg intermediate — removes k_eg entirely).
// A-row r carries batch row r>>2 for BOTH operands; C element 0 only is live.
// emb-MFMAs (reg operands) issue first, covering the h ds_read latency.
// ---------------------------------------------------------------------------
__global__ __launch_bounds__(512) void k_lstm(
    const unsigned short* __restrict__ ebf, const int* __restrict__ x,
    const float* __restrict__ Whf, const float* __restrict__ Whb,
    const float* __restrict__ Wif, const float* __restrict__ Wib,
    const float* __restrict__ bF,  const float* __restrict__ bB,
    unsigned short* __restrict__ feats)
{
    const int dir = blockIdx.y, bt = blockIdx.x;       // bt: 0..31 (4-row tiles)
    const float* __restrict__ Wh   = dir ? Whb : Whf;
    const float* __restrict__ Wi   = dir ? Wib : Wif;
    const float* __restrict__ bias = dir ? bB  : bF;
    const int tid = threadIdx.x, w = tid >> 6, L = tid & 63, l15 = L & 15, l4 = L >> 4;

    // W_hh and W_ih B-fragments in registers (128 VGPR total)
    bf16x8 Bh[4][4], Bi[4][4];
    float  bq[4];
#pragma unroll
    for (int q = 0; q < 4; ++q) {
        const int gate = q * 128 + w * 16 + l15;
        bq[q] = bias[gate];
#pragma unroll
        for (int kt = 0; kt < 4; ++kt) {
            Bh[q][kt] = cvt8(Wh + gate * 128 + kt * 32 + l4 * 8);
            Bi[q][kt] = cvt8(Wi + gate * 128 + kt * 32 + l4 * 8);
        }
    }

    __shared__ unsigned short hl[2048];   // 2 bufs x 4 rows x 256B, rotated granules
    for (int i = tid; i < 1024; i += 512) ((unsigned*)hl)[i] = 0;

    // h A-read byte offsets: A row r = l15 carries h[l15>>2]; slice kt*32+l4*8.
    const int ar = l15 >> 2;
    int rdoff[4];
#pragma unroll
    for (int kt = 0; kt < 4; ++kt) {
        int p = (kt * 4 + l4 + 2 * ar) & 15;
        rdoff[kt] = ar * 256 + p * 16;
    }
    // h write offset: row=l4, col hc (same rotation family as reads)
    const int hc = w * 16 + l15;
    const int wroff = l4 * 256 + (((hc >> 3) + 2 * l4) & 15) * 16 + (hc & 7) * 2;

    float c = 0.f;
    // token stream for the lane's A-ROW batch row (ar), embed slice l4*8
    const int* __restrict__ xrowA = x + (bt * 4 + ar) * S_LEN;
    // feats: output row bt*4+l4, col dir*128+hc
    unsigned short* fcur = feats + ((size_t)(bt * 4 + l4) * 512 + (dir ? 511 : 0)) * 256
                                 + dir * 128 + hc;
    const ptrdiff_t fstep = dir ? -256 : 256;

    // prologue: embed frags for step 0 (direct), token for step 1
    bf16x8 eA[4], eB[4];
    {
        const int tok0 = xrowA[dir ? 511 : 0];
        const unsigned short* eb = ebf + (size_t)tok0 * 128 + l4 * 8;
#pragma unroll
        for (int kt = 0; kt < 4; ++kt) eA[kt] = *(const bf16x8*)(eb + kt * 32);
    }
    int tkN = xrowA[dir ? 510 : 1];   // token for step 1

    f32x4 acc[4];
#pragma unroll
    for (int q = 0; q < 4; ++q) acc[q] = f32x4{0.f, 0.f, 0.f, 0.f};

    __syncthreads();   // covers hl zero-init

#define LSTM_STEP(T, EC, EN)                                                    \
    {                                                                           \
        const int t_ = (T);                                                     \
        const char* bufR = (const char*)hl + (t_ & 1) * 1024;                   \
        char*       bufW = (char*)hl + ((t_ & 1) ^ 1) * 1024;                   \
        /* token for t+2 (used for the gather issued at t+1) */                 \
        const int t2_ = (t_ < 510) ? (t_ + 2) : 511;                            \
        int tknew = xrowA[dir ? (511 - t2_) : t2_];                             \
        /* embed gather for step t+1 into EN (one full step of latency) */      \
        const unsigned short* eb_ = ebf + (size_t)tkN * 128 + l4 * 8;           \
        _Pragma("unroll")                                                       \
        for (int kt = 0; kt < 4; ++kt) EN[kt] = *(const bf16x8*)(eb_ + kt * 32);\
        /* h from LDS */                                                        \
        bf16x8 A_[4];                                                           \
        _Pragma("unroll")                                                       \
        for (int kt = 0; kt < 4; ++kt)                                          \
            A_[kt] = *(const bf16x8*)(bufR + rdoff[kt]);                        \
        /* gates = bias + emb@W_ih + h@W_hh (emb first: reg operands ready) */  \
        _Pragma("unroll")                                                       \
        for (int q = 0; q < 4; ++q) {                                           \
            acc[q][0] = bq[q];                                                  \
            _Pragma("unroll")                                                   \
            for (int kt = 0; kt < 4; ++kt)                                      \
                acc[q] = __builtin_amdgcn_mfma_f32_16x16x32_bf16(               \
                             EC[kt], Bi[q][kt], acc[q], 0, 0, 0);               \
            _Pragma("unroll")                                                   \
            for (int kt = 0; kt < 4; ++kt)                                      \
                acc[q] = __builtin_amdgcn_mfma_f32_16x16x32_bf16(               \
                             A_[kt], Bh[q][kt], acc[q], 0, 0, 0);               \
        }                                                                       \
        float ig = sigf(acc[0][0]);                                             \
        float fg = sigf(acc[1][0]);                                             \
        float gg = tanhf_(acc[2][0]);                                           \
        float og = sigf(acc[3][0]);                                             \
        c = fg * c + ig * gg;                                                   \
        float h_ = og * tanhf_(c);                                              \
        unsigned short hb = f2bf(h_);                                           \
        *(unsigned short*)(bufW + wroff) = hb;                                  \
        *fcur = hb; fcur += fstep;                                              \
        wg_barrier_lds();                                                       \
        tkN = tknew;                                                            \
    }

    for (int it = 0; it < 256; ++it) {
        LSTM_STEP(2 * it,     eA, eB)
        LSTM_STEP(2 * it + 1, eB, eA)
    }
#undef LSTM_STEP
}

// ---------------------------------------------------------------------------
// Kernel 2: emissions + Viterbi fused (unchanged). One WG per batch row.
// ---------------------------------------------------------------------------
__global__ __launch_bounds__(256) void k_viterbi(
    const unsigned short* __restrict__ feats, const float* __restrict__ Wout,
    const int* __restrict__ mask, const float* __restrict__ bout,
    const float* __restrict__ startt, const float* __restrict__ trans,
    const float* __restrict__ endt, float* __restrict__ out)
{
    const int b = blockIdx.x, tid = threadIdx.x;
    const int w = tid >> 6, L = tid & 63, l15 = L & 15, l4 = L >> 4;
    __shared__ float em[512 * 9];
    __shared__ int   msk[512];
    __shared__ unsigned char hist[512 * 9];
    __shared__ unsigned char Gl[32 * 12];
    __shared__ unsigned char bound[32];
    __shared__ int curS;

    bf16x8 Of[2][4];
#pragma unroll
    for (int d = 0; d < 2; ++d)
#pragma unroll
        for (int kt = 0; kt < 4; ++kt) { bf16x8 z;
#pragma unroll
            for (int i = 0; i < 8; ++i) z[i] = 0; Of[d][kt] = z; }
    float bv = 0.f;
    if (l15 < NT) {
        bv = bout[l15];
#pragma unroll
        for (int d = 0; d < 2; ++d)
#pragma unroll
            for (int kt = 0; kt < 4; ++kt)
                Of[d][kt] = cvt8(Wout + l15 * 256 + d * 128 + kt * 32 + l4 * 8);
    }

    for (int i = tid; i < 512; i += 256) msk[i] = mask[b * 512 + i];

    // emissions: wave w covers sg = w*8 .. w*8+7 (16 positions each)
#pragma unroll
    for (int i = 0; i < 8; ++i) {
        const int sg = w * 8 + i;
        const unsigned short* frow = feats + ((size_t)b * 512 + sg * 16 + l15) * 256;
        f32x4 e0 = {0, 0, 0, 0}, e1 = {0, 0, 0, 0};
#pragma unroll
        for (int kt = 0; kt < 4; ++kt) {
            bf16x8 A = *(const bf16x8*)(frow + kt * 32 + l4 * 8);
            e0 = __builtin_amdgcn_mfma_f32_16x16x32_bf16(A, Of[0][kt], e0, 0, 0, 0);
        }
#pragma unroll
        for (int kt = 0; kt < 4; ++kt) {
            bf16x8 A = *(const bf16x8*)(frow + 128 + kt * 32 + l4 * 8);
            e1 = __builtin_amdgcn_mfma_f32_16x16x32_bf16(A, Of[1][kt], e1, 0, 0, 0);
        }
        if (l15 < NT) {
#pragma unroll
            for (int j = 0; j < 4; ++j)
                em[(sg * 16 + l4 * 4 + j) * 9 + l15] = (e0[j] + e1[j]) + bv;
        }
    }
    __syncthreads();

    if (tid < 64) {   // wave 0: forward DP
        const int k = (tid < NT) ? tid : 0;
        float trk[9];
#pragma unroll
        for (int j = 0; j < NT; ++j) trk[j] = trans[j * 9 + k];
        float score = startt[k] + em[k];
        for (int t = 1; t < 512; ++t) {
            float v[9];
#pragma unroll
            for (int j = 0; j < NT; ++j) v[j] = __shfl(score, j, 64) + trk[j];
            float m01 = fmaxf(v[0], v[1]), m23 = fmaxf(v[2], v[3]);
            float m45 = fmaxf(v[4], v[5]), m67 = fmaxf(v[6], v[7]);
            float m = fmaxf(fmaxf(fmaxf(m01, m23), fmaxf(m45, m67)), v[8]);
            int bi = 0;
#pragma unroll
            for (int j = 8; j >= 0; --j) if (v[j] == m) bi = j;   // first index
            if (msk[t]) score = m + em[t * 9 + k];
            if (tid < NT) hist[t * 9 + tid] = (unsigned char)bi;
        }
        float fin = score + endt[k];
        float bs = -3e38f; int cur = 0;
#pragma unroll
        for (int j = 0; j < NT; ++j) {
            float vv = __shfl(fin, j, 64);
            if (vv > bs) { bs = vv; cur = j; }
        }
        if (tid == 0) { curS = cur; out[65536 + b] = bs; }
    }
    __syncthreads();

    // block composition maps: block m covers t in [16m+1, min(16m+16,511)]
    if (tid < 32) {
        const int m = tid;
        int G[9];
#pragma unroll
        for (int k = 0; k < NT; ++k) G[k] = k;
        const int hi = (m == 31) ? 511 : (16 * m + 16);
        for (int t = hi; t >= 16 * m + 1; --t) {
            if (msk[t]) {
#pragma unroll
                for (int k = 0; k < NT; ++k) G[k] = hist[t * 9 + G[k]];
            }
        }
#pragma unroll
        for (int k = 0; k < NT; ++k) Gl[m * 12 + k] = (unsigned char)G[k];
    }
    __syncthreads();

    if (tid == 0) {   // serial boundary walk (31 steps)
        int e = curS;
        bound[31] = (unsigned char)e;
        for (int m = 31; m >= 1; --m) { e = Gl[m * 12 + e]; bound[m - 1] = (unsigned char)e; }
        out[(size_t)b * 512] = (float)Gl[0 * 12 + e];   // c_0
    }
    __syncthreads();

    if (tid < 32) {   // lane-parallel interior backtrace
        const int m = tid;
        int ccur = bound[m];
        const int hi = (m == 31) ? 511 : (16 * m + 16);
        for (int t = hi; t >= 16 * m + 1; --t) {
            const int mt = msk[t];
            out[(size_t)b * 512 + t] = (float)(mt ? ccur : -1);
            if (mt) ccur = hist[t * 9 + ccur];
        }
    }
}

// ---------------------------------------------------------------------------
extern "C" void kernel_launch(void* const* d_in, const int* in_sizes, int n_in,
                              void* d_out, int out_size, void* d_ws, size_t ws_size,
                              hipStream_t stream) {
    const int*   x      = (const int*)d_in[0];
    const int*   mask   = (const int*)d_in[1];
    const float* embed  = (const float*)d_in[2];
    const float* Wihf   = (const float*)d_in[3];
    const float* Whhf   = (const float*)d_in[4];
    const float* bf_    = (const float*)d_in[5];
    const float* Wihb   = (const float*)d_in[6];
    const float* Whhb   = (const float*)d_in[7];
    const float* bb_    = (const float*)d_in[8];
    const float* Wout   = (const float*)d_in[9];
    const float* bout   = (const float*)d_in[10];
    const float* startt = (const float*)d_in[11];
    const float* trans  = (const float*)d_in[12];
    const float* endt   = (const float*)d_in[13];

    unsigned short* ebf   = (unsigned short*)d_ws;                             // 12.8 MB bf16
    unsigned short* feats = (unsigned short*)((char*)d_ws + (size_t)16777216); // 32 MB bf16
    float*          out   = (float*)d_out;

    k_ebf    <<<2048,        256, 0, stream>>>(embed, ebf);
    k_lstm   <<<dim3(32, 2), 512, 0, stream>>>(ebf, x, Whhf, Whhb, Wihf, Wihb, bf_, bb_, feats);
    k_viterbi<<<128,         256, 0, stream>>>(feats, Wout, mask, bout, startt, trans, endt, out);
}

// Round 13
// 432.760 us; speedup vs baseline: 1.1729x; 1.1729x over previous
//
#include <hip/hip_runtime.h>
#include <stdint.h>

#define S_LEN 512
#define NT 9

typedef __attribute__((ext_vector_type(8)))  short          bf16x8;
typedef __attribute__((ext_vector_type(4)))  float          f32x4;
typedef __attribute__((ext_vector_type(4)))  unsigned short u16x4;

static __device__ __forceinline__ unsigned short f2bf(float f) {
    union { float f; unsigned u; } c; c.f = f;
    return (unsigned short)((c.u + 0x7fffu + ((c.u >> 16) & 1u)) >> 16); // RNE
}
static __device__ __forceinline__ float bf2f(unsigned short h) {
    union { unsigned u; float f; } c; c.u = ((unsigned)h) << 16;
    return c.f;
}
static __device__ __forceinline__ bf16x8 cvt8(const float* p) {
    f32x4 a = *(const f32x4*)p, b = *(const f32x4*)(p + 4);
    bf16x8 fr;
    fr[0]=(short)f2bf(a[0]); fr[1]=(short)f2bf(a[1]); fr[2]=(short)f2bf(a[2]); fr[3]=(short)f2bf(a[3]);
    fr[4]=(short)f2bf(b[0]); fr[5]=(short)f2bf(b[1]); fr[6]=(short)f2bf(b[2]); fr[7]=(short)f2bf(b[3]);
    return fr;
}
static __device__ __forceinline__ float sigf(float x) {
    return __builtin_amdgcn_rcpf(1.0f + __expf(-x));
}
static __device__ __forceinline__ float tanhf_(float x) {
    return 1.0f - 2.0f * __builtin_amdgcn_rcpf(1.0f + __expf(2.0f * x));
}

// Raw workgroup barrier that waits ONLY LDS ops (lgkmcnt) — global loads and
// stores stay in flight across it.
static __device__ __forceinline__ void wg_barrier_lds() {
    asm volatile("s_waitcnt lgkmcnt(0)" ::: "memory");
    __builtin_amdgcn_s_barrier();
    asm volatile("" ::: "memory");
}

// ---------------------------------------------------------------------------
// Kernel 0: ebf16[v][e] = bf16(embed[v][e]) — one streaming pass. Same f2bf
// as the MFMA A-conversion everywhere, so A-fragments stay bit-identical.
// ---------------------------------------------------------------------------
__global__ __launch_bounds__(256) void k_ebf(
    const float* __restrict__ embed, unsigned short* __restrict__ ebf)
{
    const size_t n4 = 1600000;   // 50000*128/4
    for (size_t i = blockIdx.x * 256 + threadIdx.x; i < n4; i += (size_t)2048 * 256) {
        f32x4 v = *(const f32x4*)(embed + i * 4);
        u16x4 o;
        o[0] = f2bf(v[0]); o[1] = f2bf(v[1]); o[2] = f2bf(v[2]); o[3] = f2bf(v[3]);
        *(u16x4*)(ebf + i * 4) = o;
    }
}

// ---------------------------------------------------------------------------
// Kernel 1: FUSED input-gate + recurrence, TIME-BATCHED xg. 64 WGs x 4 batch
// rows. Every 4 steps, ONE 16-MFMA burst computes xa = bias + emb@W_ih^T for
// 4 steps x 4 rows with NO duplication: A-row r = emb of (batch row r>>2,
// step t0+(r&3)); lane's D element j = xg(row l4, step t0+j, gate hc,q).
// Per step: gacc[q][0] = xa[q][j], then 16 h-MFMAs (4x4, kt-major). f32 xg
// path (verified absmax 0.0 in R12). embed frags gathered one chunk (~4
// steps) ahead; tokens two chunks ahead. lgkmcnt-only barrier, 1/step.
// MFMA pipe cost: 2 waves x (16+4)/step/SIMD x ~19.4cyc ≈ 776 cyc.
// ---------------------------------------------------------------------------
__global__ __launch_bounds__(512) void k_lstm(
    const unsigned short* __restrict__ ebf, const int* __restrict__ x,
    const float* __restrict__ Whf, const float* __restrict__ Whb,
    const float* __restrict__ Wif, const float* __restrict__ Wib,
    const float* __restrict__ bF,  const float* __restrict__ bB,
    unsigned short* __restrict__ feats)
{
    const int dir = blockIdx.y, bt = blockIdx.x;       // bt: 0..31 (4-row tiles)
    const float* __restrict__ Wh   = dir ? Whb : Whf;
    const float* __restrict__ Wi   = dir ? Wib : Wif;
    const float* __restrict__ bias = dir ? bB  : bF;
    const int tid = threadIdx.x, w = tid >> 6, L = tid & 63, l15 = L & 15, l4 = L >> 4;

    // W_hh and W_ih B-fragments in registers (128 VGPR total)
    bf16x8 Bh[4][4], Bi[4][4];
    float  bq[4];
#pragma unroll
    for (int q = 0; q < 4; ++q) {
        const int gate = q * 128 + w * 16 + l15;
        bq[q] = bias[gate];
#pragma unroll
        for (int kt = 0; kt < 4; ++kt) {
            Bh[q][kt] = cvt8(Wh + gate * 128 + kt * 32 + l4 * 8);
            Bi[q][kt] = cvt8(Wi + gate * 128 + kt * 32 + l4 * 8);
        }
    }

    __shared__ unsigned short hl[2048];   // 2 bufs x 4 rows x 256B, rotated granules
    for (int i = tid; i < 1024; i += 512) ((unsigned*)hl)[i] = 0;

    // h A-read byte offsets: A row r = l15 carries h[l15>>2]; slice kt*32+l4*8.
    const int ar = l15 >> 2;
    int rdoff[4];
#pragma unroll
    for (int kt = 0; kt < 4; ++kt) {
        int p = (kt * 4 + l4 + 2 * ar) & 15;
        rdoff[kt] = ar * 256 + p * 16;
    }
    // h write offset: row=l4, col hc (same rotation family as reads)
    const int hc = w * 16 + l15;
    const int wroff = l4 * 256 + (((hc >> 3) + 2 * l4) & 15) * 16 + (hc & 7) * 2;

    float cst = 0.f;
    // xa A-row l15 = (batch row l15>>2, step-in-chunk l15&3)
    const int* __restrict__ xrowA = x + (bt * 4 + (l15 >> 2)) * S_LEN;
    const int soff = l15 & 3;
    // feats: output row bt*4+l4, col dir*128+hc
    unsigned short* fcur = feats + ((size_t)(bt * 4 + l4) * 512 + (dir ? 511 : 0)) * 256
                                 + dir * 128 + hc;
    const ptrdiff_t fstep = dir ? -256 : 256;

    // prologue: emb frags for chunk 0 (direct), token for chunk 1
    bf16x8 embA[4];
    {
        const int t0_ = soff;
        const int tok0 = xrowA[dir ? (511 - t0_) : t0_];
        const unsigned short* eb = ebf + (size_t)tok0 * 128 + l4 * 8;
#pragma unroll
        for (int kt = 0; kt < 4; ++kt) embA[kt] = *(const bf16x8*)(eb + kt * 32);
    }
    int tokN;
    {
        const int t1_ = 4 + soff;
        tokN = xrowA[dir ? (511 - t1_) : t1_];
    }

    f32x4 gacc[4];
#pragma unroll
    for (int q = 0; q < 4; ++q) gacc[q] = f32x4{0.f, 0.f, 0.f, 0.f};

    __syncthreads();   // covers hl zero-init

#define LSTM_STEP(J)                                                            \
    {                                                                           \
        const char* bufR = (const char*)hl + ((J) & 1) * 1024;                  \
        char*       bufW = (char*)hl + ((((J) & 1)) ^ 1) * 1024;                \
        bf16x8 A_[4];                                                           \
        _Pragma("unroll")                                                       \
        for (int kt = 0; kt < 4; ++kt)                                          \
            A_[kt] = *(const bf16x8*)(bufR + rdoff[kt]);                        \
        _Pragma("unroll")                                                       \
        for (int q = 0; q < 4; ++q) gacc[q][0] = xa[q][(J)];                    \
        _Pragma("unroll")                                                       \
        for (int kt = 0; kt < 4; ++kt)                                          \
            _Pragma("unroll")                                                   \
            for (int q = 0; q < 4; ++q)                                         \
                gacc[q] = __builtin_amdgcn_mfma_f32_16x16x32_bf16(              \
                              A_[kt], Bh[q][kt], gacc[q], 0, 0, 0);             \
        float ig = sigf(gacc[0][0]);                                            \
        float fg = sigf(gacc[1][0]);                                            \
        float gg = tanhf_(gacc[2][0]);                                          \
        float og = sigf(gacc[3][0]);                                            \
        cst = fg * cst + ig * gg;                                               \
        float h_ = og * tanhf_(cst);                                            \
        unsigned short hb = f2bf(h_);                                           \
        *(unsigned short*)(bufW + wroff) = hb;                                  \
        *fcur = hb; fcur += fstep;                                              \
        wg_barrier_lds();                                                       \
    }

    for (int cc = 0; cc < 128; ++cc) {
        // chunk-start: xa[q][j] = xg(row l4, step 4cc+j, gate q,hc) — 16 MFMAs,
        // kt-major (4 independent q-chains interleaved)
        f32x4 xa[4];
#pragma unroll
        for (int q = 0; q < 4; ++q) xa[q] = f32x4{ bq[q], bq[q], bq[q], bq[q] };
#pragma unroll
        for (int kt = 0; kt < 4; ++kt)
#pragma unroll
            for (int q = 0; q < 4; ++q)
                xa[q] = __builtin_amdgcn_mfma_f32_16x16x32_bf16(
                            embA[kt], Bi[q][kt], xa[q], 0, 0, 0);
        // re-gather embA for the NEXT chunk (lands during these 4 steps)
        {
            const unsigned short* eb = ebf + (size_t)tokN * 128 + l4 * 8;
#pragma unroll
            for (int kt = 0; kt < 4; ++kt) embA[kt] = *(const bf16x8*)(eb + kt * 32);
        }
        // token for chunk cc+2
        {
            int tc2 = 4 * (cc + 2) + soff;
            tc2 = (tc2 > 511) ? 511 : tc2;
            tokN = xrowA[dir ? (511 - tc2) : tc2];
        }
        LSTM_STEP(0)
        LSTM_STEP(1)
        LSTM_STEP(2)
        LSTM_STEP(3)
    }
#undef LSTM_STEP
}

// ---------------------------------------------------------------------------
// Kernel 2: emissions + Viterbi fused (unchanged). One WG per batch row.
// ---------------------------------------------------------------------------
__global__ __launch_bounds__(256) void k_viterbi(
    const unsigned short* __restrict__ feats, const float* __restrict__ Wout,
    const int* __restrict__ mask, const float* __restrict__ bout,
    const float* __restrict__ startt, const float* __restrict__ trans,
    const float* __restrict__ endt, float* __restrict__ out)
{
    const int b = blockIdx.x, tid = threadIdx.x;
    const int w = tid >> 6, L = tid & 63, l15 = L & 15, l4 = L >> 4;
    __shared__ float em[512 * 9];
    __shared__ int   msk[512];
    __shared__ unsigned char hist[512 * 9];
    __shared__ unsigned char Gl[32 * 12];
    __shared__ unsigned char bound[32];
    __shared__ int curS;

    bf16x8 Of[2][4];
#pragma unroll
    for (int d = 0; d < 2; ++d)
#pragma unroll
        for (int kt = 0; kt < 4; ++kt) { bf16x8 z;
#pragma unroll
            for (int i = 0; i < 8; ++i) z[i] = 0; Of[d][kt] = z; }
    float bv = 0.f;
    if (l15 < NT) {
        bv = bout[l15];
#pragma unroll
        for (int d = 0; d < 2; ++d)
#pragma unroll
            for (int kt = 0; kt < 4; ++kt)
                Of[d][kt] = cvt8(Wout + l15 * 256 + d * 128 + kt * 32 + l4 * 8);
    }

    for (int i = tid; i < 512; i += 256) msk[i] = mask[b * 512 + i];

    // emissions: wave w covers sg = w*8 .. w*8+7 (16 positions each)
#pragma unroll
    for (int i = 0; i < 8; ++i) {
        const int sg = w * 8 + i;
        const unsigned short* frow = feats + ((size_t)b * 512 + sg * 16 + l15) * 256;
        f32x4 e0 = {0, 0, 0, 0}, e1 = {0, 0, 0, 0};
#pragma unroll
        for (int kt = 0; kt < 4; ++kt) {
            bf16x8 A = *(const bf16x8*)(frow + kt * 32 + l4 * 8);
            e0 = __builtin_amdgcn_mfma_f32_16x16x32_bf16(A, Of[0][kt], e0, 0, 0, 0);
        }
#pragma unroll
        for (int kt = 0; kt < 4; ++kt) {
            bf16x8 A = *(const bf16x8*)(frow + 128 + kt * 32 + l4 * 8);
            e1 = __builtin_amdgcn_mfma_f32_16x16x32_bf16(A, Of[1][kt], e1, 0, 0, 0);
        }
        if (l15 < NT) {
#pragma unroll
            for (int j = 0; j < 4; ++j)
                em[(sg * 16 + l4 * 4 + j) * 9 + l15] = (e0[j] + e1[j]) + bv;
        }
    }
    __syncthreads();

    if (tid < 64) {   // wave 0: forward DP
        const int k = (tid < NT) ? tid : 0;
        float trk[9];
#pragma unroll
        for (int j = 0; j < NT; ++j) trk[j] = trans[j * 9 + k];
        float score = startt[k] + em[k];
        for (int t = 1; t < 512; ++t) {
            float v[9];
#pragma unroll
            for (int j = 0; j < NT; ++j) v[j] = __shfl(score, j, 64) + trk[j];
            float m01 = fmaxf(v[0], v[1]), m23 = fmaxf(v[2], v[3]);
            float m45 = fmaxf(v[4], v[5]), m67 = fmaxf(v[6], v[7]);
            float m = fmaxf(fmaxf(fmaxf(m01, m23), fmaxf(m45, m67)), v[8]);
            int bi = 0;
#pragma unroll
            for (int j = 8; j >= 0; --j) if (v[j] == m) bi = j;   // first index
            if (msk[t]) score = m + em[t * 9 + k];
            if (tid < NT) hist[t * 9 + tid] = (unsigned char)bi;
        }
        float fin = score + endt[k];
        float bs = -3e38f; int cur = 0;
#pragma unroll
        for (int j = 0; j < NT; ++j) {
            float vv = __shfl(fin, j, 64);
            if (vv > bs) { bs = vv; cur = j; }
        }
        if (tid == 0) { curS = cur; out[65536 + b] = bs; }
    }
    __syncthreads();

    // block composition maps: block m covers t in [16m+1, min(16m+16,511)]
    if (tid < 32) {
        const int m = tid;
        int G[9];
#pragma unroll
        for (int k = 0; k < NT; ++k) G[k] = k;
        const int hi = (m == 31) ? 511 : (16 * m + 16);
        for (int t = hi; t >= 16 * m + 1; --t) {
            if (msk[t]) {
#pragma unroll
                for (int k = 0; k < NT; ++k) G[k] = hist[t * 9 + G[k]];
            }
        }
#pragma unroll
        for (int k = 0; k < NT; ++k) Gl[m * 12 + k] = (unsigned char)G[k];
    }
    __syncthreads();

    if (tid == 0) {   // serial boundary walk (31 steps)
        int e = curS;
        bound[31] = (unsigned char)e;
        for (int m = 31; m >= 1; --m) { e = Gl[m * 12 + e]; bound[m - 1] = (unsigned char)e; }
        out[(size_t)b * 512] = (float)Gl[0 * 12 + e];   // c_0
    }
    __syncthreads();

    if (tid < 32) {   // lane-parallel interior backtrace
        const int m = tid;
        int ccur = bound[m];
        const int hi = (m == 31) ? 511 : (16 * m + 16);
        for (int t = hi; t >= 16 * m + 1; --t) {
            const int mt = msk[t];
            out[(size_t)b * 512 + t] = (float)(mt ? ccur : -1);
            if (mt) ccur = hist[t * 9 + ccur];
        }
    }
}

// ---------------------------------------------------------------------------
extern "C" void kernel_launch(void* const* d_in, const int* in_sizes, int n_in,
                              void* d_out, int out_size, void* d_ws, size_t ws_size,
                              hipStream_t stream) {
    const int*   x      = (const int*)d_in[0];
    const int*   mask   = (const int*)d_in[1];
    const float* embed  = (const float*)d_in[2];
    const float* Wihf   = (const float*)d_in[3];
    const float* Whhf   = (const float*)d_in[4];
    const float* bf_    = (const float*)d_in[5];
    const float* Wihb   = (const float*)d_in[6];
    const float* Whhb   = (const float*)d_in[7];
    const float* bb_    = (const float*)d_in[8];
    const float* Wout   = (const float*)d_in[9];
    const float* bout   = (const float*)d_in[10];
    const float* startt = (const float*)d_in[11];
    const float* trans  = (const float*)d_in[12];
    const float* endt   = (const float*)d_in[13];

    unsigned short* ebf   = (unsigned short*)d_ws;                             // 12.8 MB bf16
    unsigned short* feats = (unsigned short*)((char*)d_ws + (size_t)16777216); // 32 MB bf16
    float*          out   = (float*)d_out;

    k_ebf    <<<2048,        256, 0, stream>>>(embed, ebf);
    k_lstm   <<<dim3(32, 2), 512, 0, stream>>>(ebf, x, Whhf, Whhb, Wihf, Wihb, bf_, bb_, feats);
    k_viterbi<<<128,         256, 0, stream>>>(feats, Wout, mask, bout, startt, trans, endt, out);
}